// Round 1
// baseline (329.448 us; speedup 1.0000x reference)
//
#include <hip/hip_runtime.h>
#include <hip/hip_bf16.h>

typedef __attribute__((ext_vector_type(8))) short short8;
typedef __attribute__((ext_vector_type(4))) float f32x4;

#define MFMA16(a, b, c) __builtin_amdgcn_mfma_f32_16x16x32_bf16(a, b, c, 0, 0, 0)

typedef __attribute__((address_space(1))) const unsigned int GU32;
typedef __attribute__((address_space(3))) unsigned int LU32;
#define GLOAD16(g, l) __builtin_amdgcn_global_load_lds((GU32*)(g), (LU32*)(l), 16, 0, 0)

__device__ __forceinline__ unsigned short f2bf(float f) {
    union { float f; unsigned u; } a; a.f = f;
    unsigned r = a.u + 0x7fffu + ((a.u >> 16) & 1u);   // RNE
    return (unsigned short)(r >> 16);
}

// ---------------------------------------------------------------- convert f32 -> bf16
__global__ void cvt_bf16_k(const float* __restrict__ s, unsigned short* __restrict__ d, int n4) {
    int i = blockIdx.x * 256 + threadIdx.x;
    if (i >= n4) return;
    float4 v = reinterpret_cast<const float4*>(s)[i];
    ushort4 o;
    o.x = f2bf(v.x); o.y = f2bf(v.y); o.z = f2bf(v.z); o.w = f2bf(v.w);
    reinterpret_cast<ushort4*>(d)[i] = o;
}

// ---------------------------------------------------------------- GEMM: C[n][m] = A[n][:] . B[m][:] + bias[m]
// A [4096][1024] bf16, B [1024][1024] bf16 (row-major, acts as B^T), out [4096][1024]
// 128x128 tile, BK=32, 4 waves (2x2), each wave 64x64 (4x4 frags of 16x16x32)
template<int F32OUT>
__global__ __launch_bounds__(256) void gemm_bt_k(
    const unsigned short* __restrict__ A,
    const unsigned short* __restrict__ B0, const unsigned short* __restrict__ B1,
    const unsigned short* __restrict__ B2,
    const float* __restrict__ bias0, const float* __restrict__ bias1, const float* __restrict__ bias2,
    void* o0, void* o1, void* o2)
{
    const unsigned short* B = blockIdx.z == 0 ? B0 : (blockIdx.z == 1 ? B1 : B2);
    const float* bias       = blockIdx.z == 0 ? bias0 : (blockIdx.z == 1 ? bias1 : bias2);
    void* outp              = blockIdx.z == 0 ? o0 : (blockIdx.z == 1 ? o1 : o2);

    __shared__ unsigned short As[128 * 32];
    __shared__ unsigned short Bs[128 * 32];

    const int tid = threadIdx.x;
    const int wid = tid >> 6, lane = tid & 63;
    const int lr = lane & 15, g = lane >> 4;
    const int wr = wid >> 1, wc = wid & 1;
    const int row0 = blockIdx.x * 128;
    const int col0 = blockIdx.y * 128;

    // staging: thread t covers LDS bytes t*16 (row t/4, cols (t%4)*8 .. +7), two instrs (rows 0-63, 64-127)
    const int srow = tid >> 2;
    const int scol = (tid & 3) * 8;
    const unsigned short* aS0 = A + (row0 + srow) * 1024 + scol;
    const unsigned short* aS1 = aS0 + 64 * 1024;
    const unsigned short* bS0 = B + (col0 + srow) * 1024 + scol;
    const unsigned short* bS1 = bS0 + 64 * 1024;
    unsigned short* ldsA0 = As + wid * 512;
    unsigned short* ldsA1 = As + 2048 + wid * 512;
    unsigned short* ldsB0 = Bs + wid * 512;
    unsigned short* ldsB1 = Bs + 2048 + wid * 512;

    f32x4 acc[4][4] = {};

    for (int k0 = 0; k0 < 1024; k0 += 32) {
        __syncthreads();
        GLOAD16(aS0 + k0, ldsA0);
        GLOAD16(aS1 + k0, ldsA1);
        GLOAD16(bS0 + k0, ldsB0);
        GLOAD16(bS1 + k0, ldsB1);
        __syncthreads();
        short8 af[4], bf[4];
#pragma unroll
        for (int m = 0; m < 4; ++m)
            af[m] = *(const short8*)(As + (wr * 64 + m * 16 + lr) * 32 + g * 8);
#pragma unroll
        for (int n = 0; n < 4; ++n)
            bf[n] = *(const short8*)(Bs + (wc * 64 + n * 16 + lr) * 32 + g * 8);
#pragma unroll
        for (int m = 0; m < 4; ++m)
#pragma unroll
            for (int n = 0; n < 4; ++n)
                acc[m][n] = MFMA16(af[m], bf[n], acc[m][n]);
    }

#pragma unroll
    for (int n = 0; n < 4; ++n) {
        const int col = col0 + wc * 64 + n * 16 + lr;
        const float bv = bias[col];
#pragma unroll
        for (int m = 0; m < 4; ++m)
#pragma unroll
            for (int r = 0; r < 4; ++r) {
                const int row = row0 + wr * 64 + m * 16 + g * 4 + r;
                const float v = acc[m][n][r] + bv;
                if (F32OUT) ((float*)outp)[row * 1024 + col] = v;
                else        ((unsigned short*)outp)[row * 1024 + col] = f2bf(v);
            }
    }
}

// ---------------------------------------------------------------- transpose bf16 [4096][1024] -> [1024][4096]
__global__ __launch_bounds__(256) void transpose_k(const unsigned short* __restrict__ in,
                                                   unsigned short* __restrict__ out) {
    __shared__ unsigned short t[64][72];
    const int tid = threadIdx.x;
    const int r0 = blockIdx.x * 64;   // token dim
    const int c0 = blockIdx.y * 64;   // feature dim
    {
        const int r = tid >> 2, cc = (tid & 3) * 16;
        const unsigned short* p = in + (r0 + r) * 1024 + c0 + cc;
        *(short8*)&t[r][cc]     = *(const short8*)p;
        *(short8*)&t[r][cc + 8] = *(const short8*)(p + 8);
    }
    __syncthreads();
    {
        const int c = tid >> 2, rr = (tid & 3) * 16;
        short8 v0, v1;
#pragma unroll
        for (int j = 0; j < 8; ++j) {
            v0[j] = (short)t[rr + j][c];
            v1[j] = (short)t[rr + 8 + j][c];
        }
        unsigned short* q = out + (c0 + c) * 4096 + r0 + rr;
        *(short8*)q       = v0;
        *(short8*)(q + 8) = v1;
    }
}

// ---------------------------------------------------------------- flash attention
// grid (64 q-tiles, 16 heads), 256 thr. Q,K [4096][1024] bf16 ([n][h*64+d]); Vt [1024][4096] bf16 ([h*64+d][n]).
// Per wave: 16 q rows. KV tile 64. K/V staged swizzled (byte ^= (row&7)<<4) via pre-swizzled global source.
__global__ __launch_bounds__(256) void attn_k(
    const unsigned short* __restrict__ Q, const unsigned short* __restrict__ K,
    const unsigned short* __restrict__ Vt, unsigned short* __restrict__ C)
{
    __shared__ unsigned short Ks[64 * 64];
    __shared__ unsigned short Vs[64 * 64];
    __shared__ unsigned short Ps[4][16 * 64];

    const int h = blockIdx.y;
    const int q0 = blockIdx.x * 64;
    const int tid = threadIdx.x, wid = tid >> 6, lane = tid & 63;
    const int lr = lane & 15, g = lane >> 4;
    const int swz = (lr & 7) << 4;

    // Q A-frags hoisted: row = q0+wid*16+lr, d = ks*32 + g*8 .. +7
    short8 qf[2];
    {
        const unsigned short* qp = Q + (q0 + wid * 16 + lr) * 1024 + h * 64 + g * 8;
        qf[0] = *(const short8*)qp;
        qf[1] = *(const short8*)(qp + 32);
    }

    f32x4 acc[4] = {};
    float mrun[4], lrun[4];
#pragma unroll
    for (int r = 0; r < 4; ++r) { mrun[r] = -1e30f; lrun[r] = 0.f; }

    // staging source (pre-swizzled so linear LDS write == swizzled layout)
    const int srow = tid >> 3;                       // row within half tile (0..31)
    const int sinn = (tid & 7) * 16;                 // byte offset in 128B row
    const int dK = ((sinn ^ ((srow & 7) << 4)) >> 1);
    const unsigned short* srcK0 = K + srow * 1024 + h * 64 + dK;
    const unsigned short* srcK1 = K + (srow + 32) * 1024 + h * 64 + dK;
    const unsigned short* srcV0 = Vt + (h * 64 + srow) * 4096 + dK;
    const unsigned short* srcV1 = Vt + (h * 64 + srow + 32) * 4096 + dK;
    unsigned short* ldsK0 = Ks + wid * 512;
    unsigned short* ldsK1 = Ks + 2048 + wid * 512;
    unsigned short* ldsV0 = Vs + wid * 512;
    unsigned short* ldsV1 = Vs + 2048 + wid * 512;
    unsigned short* myPs = Ps[wid];

    for (int kv0 = 0; kv0 < 4096; kv0 += 64) {
        __syncthreads();
        GLOAD16(srcK0 + kv0 * 1024, ldsK0);
        GLOAD16(srcK1 + kv0 * 1024, ldsK1);
        GLOAD16(srcV0 + kv0, ldsV0);
        GLOAD16(srcV1 + kv0, ldsV1);
        __syncthreads();

        // S[q][key] = Q . K^T : A=Q frag, B: col=key=nf*16+lr, k=d
        f32x4 s[4] = {};
#pragma unroll
        for (int ks = 0; ks < 2; ++ks)
#pragma unroll
            for (int nf = 0; nf < 4; ++nf) {
                const short8 kb = *(const short8*)(Ks + ((((nf * 16 + lr) * 128) + ks * 64 + g * 16) ^ swz) / 2);
                s[nf] = MFMA16(qf[ks], kb, s[nf]);
            }

        // in-register online softmax: lane holds S[q=g*4+r][key=nf*16+lr], scaled
        float sv[4][4];
#pragma unroll
        for (int nf = 0; nf < 4; ++nf)
#pragma unroll
            for (int r = 0; r < 4; ++r) sv[nf][r] = s[nf][r] * 0.125f;

        float tmax[4];
#pragma unroll
        for (int r = 0; r < 4; ++r)
            tmax[r] = fmaxf(fmaxf(sv[0][r], sv[1][r]), fmaxf(sv[2][r], sv[3][r]));
#pragma unroll
        for (int off = 1; off < 16; off <<= 1)
#pragma unroll
            for (int r = 0; r < 4; ++r)
                tmax[r] = fmaxf(tmax[r], __shfl_xor(tmax[r], off));

        float alpha[4], tsum[4] = {0.f, 0.f, 0.f, 0.f};
        unsigned short pb[4][4];
#pragma unroll
        for (int r = 0; r < 4; ++r) {
            const float mnew = fmaxf(mrun[r], tmax[r]);
            alpha[r] = __expf(mrun[r] - mnew);
            mrun[r] = mnew;
        }
#pragma unroll
        for (int nf = 0; nf < 4; ++nf)
#pragma unroll
            for (int r = 0; r < 4; ++r) {
                const float p = __expf(sv[nf][r] - mrun[r]);
                tsum[r] += p;
                pb[nf][r] = f2bf(p);
            }
#pragma unroll
        for (int off = 1; off < 16; off <<= 1)
#pragma unroll
            for (int r = 0; r < 4; ++r)
                tsum[r] += __shfl_xor(tsum[r], off);
#pragma unroll
        for (int r = 0; r < 4; ++r) lrun[r] = lrun[r] * alpha[r] + tsum[r];

        // transpose P through per-wave swizzled LDS: write (q=g*4+r, key=nf*16+lr)
#pragma unroll
        for (int nf = 0; nf < 4; ++nf)
#pragma unroll
            for (int r = 0; r < 4; ++r) {
                const int qr = g * 4 + r;
                myPs[((qr * 128 + (nf * 16 + lr) * 2) ^ ((qr & 7) << 4)) >> 1] = pb[nf][r];
            }

#pragma unroll
        for (int nf = 0; nf < 4; ++nf)
#pragma unroll
            for (int r = 0; r < 4; ++r) acc[nf][r] *= alpha[r];

        // ctx += P . V : A: row=q=lr, k=key contiguous; B: col=d=nf*16+lr, k=key contiguous (Vs = V^T tile)
#pragma unroll
        for (int ks = 0; ks < 2; ++ks) {
            const short8 pa = *(const short8*)(myPs + (((lr * 128) + ks * 64 + g * 16) ^ swz) / 2);
#pragma unroll
            for (int nf = 0; nf < 4; ++nf) {
                const short8 vb = *(const short8*)(Vs + ((((nf * 16 + lr) * 128) + ks * 64 + g * 16) ^ swz) / 2);
                acc[nf] = MFMA16(pa, vb, acc[nf]);
            }
        }
    }

    float linv[4];
#pragma unroll
    for (int r = 0; r < 4; ++r) linv[r] = 1.f / lrun[r];
#pragma unroll
    for (int nf = 0; nf < 4; ++nf)
#pragma unroll
        for (int r = 0; r < 4; ++r) {
            const int n = q0 + wid * 16 + g * 4 + r;
            const int c = h * 64 + nf * 16 + lr;
            C[n * 1024 + c] = f2bf(acc[nf][r] * linv[r]);
        }
}

// ---------------------------------------------------------------- launch
extern "C" void kernel_launch(void* const* d_in, const int* in_sizes, int n_in,
                              void* d_out, int out_size, void* d_ws, size_t ws_size,
                              hipStream_t stream) {
    const float* x  = (const float*)d_in[0];
    const float* Wq = (const float*)d_in[1];
    const float* bq = (const float*)d_in[2];
    const float* Wk = (const float*)d_in[3];
    const float* bk = (const float*)d_in[4];
    const float* Wv = (const float*)d_in[5];
    const float* bv = (const float*)d_in[6];
    const float* Wo = (const float*)d_in[7];
    const float* bo = (const float*)d_in[8];
    float* out = (float*)d_out;

    const size_t MB = 1ull << 20;
    char* ws = (char*)d_ws;
    unsigned short* xb  = (unsigned short*)(ws);            // 8MB; reused as Vt after QKV GEMM
    unsigned short* Wqb = (unsigned short*)(ws + 8 * MB);
    unsigned short* Wkb = (unsigned short*)(ws + 10 * MB);
    unsigned short* Wvb = (unsigned short*)(ws + 12 * MB);
    unsigned short* Wob = (unsigned short*)(ws + 14 * MB);
    unsigned short* Qb  = (unsigned short*)(ws + 16 * MB);  // 8MB
    unsigned short* Kb  = (unsigned short*)(ws + 24 * MB);  // 8MB
    unsigned short* Vb  = (unsigned short*)(ws + 32 * MB);  // 8MB; reused as ctx after transpose
    unsigned short* Vtb = xb;
    unsigned short* Cb  = Vb;

    // 1. convert to bf16
    cvt_bf16_k<<<4096, 256, 0, stream>>>(x,  xb,  4096 * 1024 / 4);
    cvt_bf16_k<<<1024, 256, 0, stream>>>(Wq, Wqb, 1024 * 1024 / 4);
    cvt_bf16_k<<<1024, 256, 0, stream>>>(Wk, Wkb, 1024 * 1024 / 4);
    cvt_bf16_k<<<1024, 256, 0, stream>>>(Wv, Wvb, 1024 * 1024 / 4);
    cvt_bf16_k<<<1024, 256, 0, stream>>>(Wo, Wob, 1024 * 1024 / 4);

    // 2. QKV projections (one launch, z selects)
    gemm_bt_k<0><<<dim3(32, 8, 3), 256, 0, stream>>>(xb, Wqb, Wkb, Wvb, bq, bk, bv, Qb, Kb, Vb);

    // 3. V -> V^T
    transpose_k<<<dim3(64, 16), 256, 0, stream>>>(Vb, Vtb);

    // 4. attention -> ctx (over Vb slot)
    attn_k<<<dim3(64, 16), 256, 0, stream>>>(Qb, Kb, Vtb, Cb);

    // 5. output projection (f32 out)
    gemm_bt_k<1><<<dim3(32, 8, 1), 256, 0, stream>>>(Cb, Wob, Wob, Wob, bo, bo, bo, out, out, out);
}

// Round 2
// 208.038 us; speedup vs baseline: 1.5836x; 1.5836x over previous
//
#include <hip/hip_runtime.h>
#include <hip/hip_bf16.h>

typedef __attribute__((ext_vector_type(8))) short short8;
typedef __attribute__((ext_vector_type(4))) float f32x4;
typedef __attribute__((ext_vector_type(16))) float f32x16;

#define MFMA16(a, b, c) __builtin_amdgcn_mfma_f32_16x16x32_bf16(a, b, c, 0, 0, 0)
#define MFMA32(a, b, c) __builtin_amdgcn_mfma_f32_32x32x16_bf16(a, b, c, 0, 0, 0)

typedef __attribute__((address_space(1))) const unsigned int GU32;
typedef __attribute__((address_space(3))) unsigned int LU32;
#define GLOAD16(g, l) __builtin_amdgcn_global_load_lds((GU32*)(g), (LU32*)(l), 16, 0, 0)

__device__ __forceinline__ unsigned short f2bf(float f) {
    union { float f; unsigned u; } a; a.f = f;
    unsigned r = a.u + 0x7fffu + ((a.u >> 16) & 1u);   // RNE
    return (unsigned short)(r >> 16);
}

__device__ __forceinline__ unsigned pk2(float a, float b) {
    __hip_bfloat162 h = __float22bfloat162_rn(make_float2(a, b));   // v_cvt_pk_bf16_f32
    union { __hip_bfloat162 h; unsigned u; } cv; cv.h = h; return cv.u;
}

// ---------------------------------------------------------------- convert f32 -> bf16
__global__ void cvt_bf16_k(const float* __restrict__ s, unsigned short* __restrict__ d, int n4) {
    int i = blockIdx.x * 256 + threadIdx.x;
    if (i >= n4) return;
    float4 v = reinterpret_cast<const float4*>(s)[i];
    ushort4 o;
    o.x = f2bf(v.x); o.y = f2bf(v.y); o.z = f2bf(v.z); o.w = f2bf(v.w);
    reinterpret_cast<ushort4*>(d)[i] = o;
}

// ---------------------------------------------------------------- GEMM: out[n][m] = (A[n][:] . B[m][:] + bias[m]) * scale
// 128x128 tile, BK=32, 2-phase double-buffered staging, 4 waves (2x2), 4x4 16x16x32 frags/wave
template<int F32OUT>
__global__ __launch_bounds__(256) void gemm_bt_k(
    const unsigned short* __restrict__ A,
    const unsigned short* __restrict__ B0, const unsigned short* __restrict__ B1,
    const unsigned short* __restrict__ B2,
    const float* __restrict__ bias0, const float* __restrict__ bias1, const float* __restrict__ bias2,
    float s0, float s1, float s2,
    void* o0, void* o1, void* o2)
{
    const int z = blockIdx.z;
    const unsigned short* B = z == 0 ? B0 : (z == 1 ? B1 : B2);
    const float* bias       = z == 0 ? bias0 : (z == 1 ? bias1 : bias2);
    const float scl         = z == 0 ? s0 : (z == 1 ? s1 : s2);
    void* outp              = z == 0 ? o0 : (z == 1 ? o1 : o2);

    __shared__ unsigned short As[2][4096];
    __shared__ unsigned short Bs[2][4096];

    const int tid = threadIdx.x;
    const int wid = tid >> 6, lane = tid & 63;
    const int lr = lane & 15, g = lane >> 4;
    const int wr = wid >> 1, wc = wid & 1;
    const int row0 = blockIdx.x * 128;
    const int col0 = blockIdx.y * 128;

    // staging: thread t covers LDS bytes t*16 (row t/4, cols (t%4)*8 .. +7), two instrs per operand
    const int srow = tid >> 2;
    const int scol = (tid & 3) * 8;
    const unsigned short* aS0 = A + (row0 + srow) * 1024 + scol;
    const unsigned short* aS1 = aS0 + 64 * 1024;
    const unsigned short* bS0 = B + (col0 + srow) * 1024 + scol;
    const unsigned short* bS1 = bS0 + 64 * 1024;
    unsigned short* lA = &As[0][wid * 512];
    unsigned short* lB = &Bs[0][wid * 512];

#define GSTG(BUF, K0) do {                              \
        GLOAD16(aS0 + (K0), lA + (BUF) * 4096);         \
        GLOAD16(aS1 + (K0), lA + (BUF) * 4096 + 2048);  \
        GLOAD16(bS0 + (K0), lB + (BUF) * 4096);         \
        GLOAD16(bS1 + (K0), lB + (BUF) * 4096 + 2048);  \
    } while (0)

    f32x4 acc[4][4] = {};

    auto cmp = [&](const unsigned short* Ab, const unsigned short* Bb) {
        short8 af[4], bfr[4];
#pragma unroll
        for (int m = 0; m < 4; ++m)
            af[m] = *(const short8*)(Ab + (wr * 64 + m * 16 + lr) * 32 + g * 8);
#pragma unroll
        for (int n = 0; n < 4; ++n)
            bfr[n] = *(const short8*)(Bb + (wc * 64 + n * 16 + lr) * 32 + g * 8);
#pragma unroll
        for (int m = 0; m < 4; ++m)
#pragma unroll
            for (int n = 0; n < 4; ++n)
                acc[m][n] = MFMA16(af[m], bfr[n], acc[m][n]);
    };

    GSTG(0, 0);
    __syncthreads();
    for (int k0 = 0; k0 < 1024; k0 += 64) {
        if (k0 + 32 < 1024) GSTG(1, k0 + 32);
        cmp(As[0], Bs[0]);
        __syncthreads();
        if (k0 + 64 < 1024) GSTG(0, k0 + 64);
        cmp(As[1], Bs[1]);
        __syncthreads();
    }
#undef GSTG

#pragma unroll
    for (int n = 0; n < 4; ++n) {
        const int col = col0 + wc * 64 + n * 16 + lr;
        const float bv = bias[col];
#pragma unroll
        for (int m = 0; m < 4; ++m)
#pragma unroll
            for (int r = 0; r < 4; ++r) {
                const int row = row0 + wr * 64 + m * 16 + g * 4 + r;
                const float v = (acc[m][n][r] + bv) * scl;
                if (F32OUT) ((float*)outp)[row * 1024 + col] = v;
                else        ((unsigned short*)outp)[row * 1024 + col] = f2bf(v);
            }
    }
}

// ---------------------------------------------------------------- transpose bf16 [4096][1024] -> [1024][4096]
__global__ __launch_bounds__(256) void transpose_k(const unsigned short* __restrict__ in,
                                                   unsigned short* __restrict__ out) {
    __shared__ unsigned short t[64][72];
    const int tid = threadIdx.x;
    const int r0 = blockIdx.x * 64;
    const int c0 = blockIdx.y * 64;
    {
        const int r = tid >> 2, cc = (tid & 3) * 16;
        const unsigned short* p = in + (r0 + r) * 1024 + c0 + cc;
        *(short8*)&t[r][cc]     = *(const short8*)p;
        *(short8*)&t[r][cc + 8] = *(const short8*)(p + 8);
    }
    __syncthreads();
    {
        const int c = tid >> 2, rr = (tid & 3) * 16;
        short8 v0, v1;
#pragma unroll
        for (int j = 0; j < 8; ++j) {
            v0[j] = (short)t[rr + j][c];
            v1[j] = (short)t[rr + 8 + j][c];
        }
        unsigned short* q = out + (c0 + c) * 4096 + r0 + rr;
        *(short8*)q       = v0;
        *(short8*)(q + 8) = v1;
    }
}

// ---------------------------------------------------------------- flash attention, swapped-operand 32x32 form
// grid (32 q-tiles of 128, 16 heads), 256 thr = 4 waves, QBLK=32 q-rows/wave, KVBLK=64.
// Q pre-scaled by 0.125*log2e in projection; softmax in exp2 domain, fully in-register.
// S^T = mfma(K,Q): lane q = lane&31, rows(keys) = (reg&3)+8*(reg>>2)+4*hi.
// ctx^T = mfma(V^T, P): acc col = q = lane&31 -> alpha/l are lane-local scalars.
__global__ __launch_bounds__(256) void attn2_k(
    const unsigned short* __restrict__ Q, const unsigned short* __restrict__ K,
    const unsigned short* __restrict__ Vt, unsigned short* __restrict__ C)
{
    __shared__ unsigned short Ks[2][4096];   // [key 0..63][d 0..63], XOR-swizzled rows
    __shared__ unsigned short Vs[2][4096];   // [d 0..63][key 0..63], XOR-swizzled rows

    const int h = blockIdx.y;
    const int q0 = blockIdx.x * 128;
    const int tid = threadIdx.x, w = tid >> 6, lane = tid & 63;
    const int l31 = lane & 31, hi = lane >> 5;
    const int swz = (l31 & 7) << 4;

    // ---- staging setup (pre-swizzled global source, linear LDS dest)
    const int sr = tid >> 3;              // tile row 0..31 (instr0); +32 for instr1
    const int sb = (tid & 7) * 16;        // byte within 128B row
    const int sc = (sb ^ ((sr & 7) << 4)) >> 1;
    const unsigned short* gK0 = K  + sr * 1024 + h * 64 + sc;
    const unsigned short* gK1 = K  + (sr + 32) * 1024 + h * 64 + sc;
    const unsigned short* gV0 = Vt + (h * 64 + sr) * 4096 + sc;
    const unsigned short* gV1 = Vt + (h * 64 + sr + 32) * 4096 + sc;
    unsigned short* kd = &Ks[0][w * 512];
    unsigned short* vd = &Vs[0][w * 512];

#define ASTAGE(BUF, KV) do {                                  \
        GLOAD16(gK0 + (KV) * 1024, kd + (BUF) * 4096);        \
        GLOAD16(gK1 + (KV) * 1024, kd + (BUF) * 4096 + 2048); \
        GLOAD16(gV0 + (KV),        vd + (BUF) * 4096);        \
        GLOAD16(gV1 + (KV),        vd + (BUF) * 4096 + 2048); \
    } while (0)

    // ---- Q fragments (B-operand): row q = q0+w*32+l31, k(d) = c*16 + hi*8 + j
    short8 qf[4];
    {
        const unsigned short* qp = Q + (q0 + w * 32 + l31) * 1024 + h * 64 + hi * 8;
#pragma unroll
        for (int c = 0; c < 4; ++c) qf[c] = *(const short8*)(qp + c * 16);
    }

    int koff[4];
#pragma unroll
    for (int c = 0; c < 4; ++c) koff[c] = ((c * 32 + hi * 16) ^ swz) >> 1;

    f32x16 acc0 = {}, acc1 = {};
    float m = -1e30f, l = 0.f;

    auto tile = [&](const unsigned short* Kc, const unsigned short* Vc) {
        // QK^T (swapped): S^T[key][q]
        f32x16 st0 = {}, st1 = {};
#pragma unroll
        for (int c = 0; c < 4; ++c) {
            st0 = MFMA32(*(const short8*)(Kc + l31 * 64 + koff[c]),        qf[c], st0);
            st1 = MFMA32(*(const short8*)(Kc + 2048 + l31 * 64 + koff[c]), qf[c], st1);
        }
        // online softmax, exp2 domain; state lane-local for q = lane&31
        float mx = -1e30f;
#pragma unroll
        for (int i = 0; i < 16; ++i) mx = fmaxf(mx, fmaxf(st0[i], st1[i]));
        mx = fmaxf(mx, __shfl_xor(mx, 32));
        if (__any(mx > m + 8.f)) {                         // defer-max THR=8
            const float mn = fmaxf(m, mx);
            const float al = __builtin_amdgcn_exp2f(m - mn);
            m = mn; l *= al;
#pragma unroll
            for (int i = 0; i < 16; ++i) { acc0[i] *= al; acc1[i] *= al; }
        }
        float p[32];
#pragma unroll
        for (int i = 0; i < 16; ++i) {
            p[i]      = __builtin_amdgcn_exp2f(st0[i] - m);
            p[16 + i] = __builtin_amdgcn_exp2f(st1[i] - m);
        }
        float ts = 0.f;
#pragma unroll
        for (int i = 0; i < 32; ++i) ts += p[i];
        ts += __shfl_xor(ts, 32);
        l += ts;
        // pack P to bf16 pairs: wv[2T+u] covers slots 8T+4hi+2u..+1
        unsigned wv[16];
#pragma unroll
        for (int T = 0; T < 8; ++T) {
            const int base = (T >> 2) * 16 + (T & 3) * 4;
            wv[T * 2]     = pk2(p[base],     p[base + 1]);
            wv[T * 2 + 1] = pk2(p[base + 2], p[base + 3]);
        }
        // PV: ctx^T += V^T . P ; P frag (B): row q=l31, k(slot) = c*16 + hi*8 + j
#pragma unroll
        for (int c = 0; c < 4; ++c) {
            const unsigned a0 = wv[4 * c + 0], a1 = wv[4 * c + 1];   // own slots 16c+4hi..+3
            const unsigned b0 = wv[4 * c + 2], b1 = wv[4 * c + 3];   // own slots 16c+8+4hi..+3
            const unsigned x0 = (unsigned)__shfl_xor((int)(hi ? a0 : b0), 32);
            const unsigned x1 = (unsigned)__shfl_xor((int)(hi ? a1 : b1), 32);
            union { unsigned u[4]; short8 s; } pf;
            pf.u[0] = hi ? x0 : a0;
            pf.u[1] = hi ? x1 : a1;
            pf.u[2] = hi ? b0 : x0;
            pf.u[3] = hi ? b1 : x1;
            acc0 = MFMA32(*(const short8*)(Vc + l31 * 64 + koff[c]),        pf.s, acc0);
            acc1 = MFMA32(*(const short8*)(Vc + 2048 + l31 * 64 + koff[c]), pf.s, acc1);
        }
    };

    ASTAGE(0, 0);
    __syncthreads();
    for (int kv = 0; kv < 4096; kv += 128) {
        if (kv + 64 < 4096) ASTAGE(1, kv + 64);
        tile(Ks[0], Vs[0]);
        __syncthreads();
        if (kv + 128 < 4096) ASTAGE(0, kv + 128);
        tile(Ks[1], Vs[1]);
        __syncthreads();
    }
#undef ASTAGE

    // epilogue: lane holds ctx^T[d][q=l31], d = dt*32 + rq*8 + 4*hi + e
    const float linv = 1.f / l;
    unsigned short* Cp = C + (q0 + w * 32 + l31) * 1024 + h * 64;
#pragma unroll
    for (int dt = 0; dt < 2; ++dt)
#pragma unroll
        for (int rq = 0; rq < 4; ++rq) {
            const f32x16& a = dt ? acc1 : acc0;
            uint2 o;
            o.x = pk2(a[rq * 4 + 0] * linv, a[rq * 4 + 1] * linv);
            o.y = pk2(a[rq * 4 + 2] * linv, a[rq * 4 + 3] * linv);
            *(uint2*)(Cp + dt * 32 + rq * 8 + hi * 4) = o;
        }
}

// ---------------------------------------------------------------- launch
extern "C" void kernel_launch(void* const* d_in, const int* in_sizes, int n_in,
                              void* d_out, int out_size, void* d_ws, size_t ws_size,
                              hipStream_t stream) {
    const float* x  = (const float*)d_in[0];
    const float* Wq = (const float*)d_in[1];
    const float* bq = (const float*)d_in[2];
    const float* Wk = (const float*)d_in[3];
    const float* bk = (const float*)d_in[4];
    const float* Wv = (const float*)d_in[5];
    const float* bv = (const float*)d_in[6];
    const float* Wo = (const float*)d_in[7];
    const float* bo = (const float*)d_in[8];
    float* out = (float*)d_out;

    const size_t MB = 1ull << 20;
    char* ws = (char*)d_ws;
    unsigned short* xb  = (unsigned short*)(ws);            // 8MB; reused as Vt after QKV GEMM
    unsigned short* Wqb = (unsigned short*)(ws + 8 * MB);
    unsigned short* Wkb = (unsigned short*)(ws + 10 * MB);
    unsigned short* Wvb = (unsigned short*)(ws + 12 * MB);
    unsigned short* Wob = (unsigned short*)(ws + 14 * MB);
    unsigned short* Qb  = (unsigned short*)(ws + 16 * MB);
    unsigned short* Kb  = (unsigned short*)(ws + 24 * MB);
    unsigned short* Vb  = (unsigned short*)(ws + 32 * MB);  // reused as ctx after transpose
    unsigned short* Vtb = xb;
    unsigned short* Cb  = Vb;

    // 1. convert to bf16
    cvt_bf16_k<<<4096, 256, 0, stream>>>(x,  xb,  4096 * 1024 / 4);
    cvt_bf16_k<<<1024, 256, 0, stream>>>(Wq, Wqb, 1024 * 1024 / 4);
    cvt_bf16_k<<<1024, 256, 0, stream>>>(Wk, Wkb, 1024 * 1024 / 4);
    cvt_bf16_k<<<1024, 256, 0, stream>>>(Wv, Wvb, 1024 * 1024 / 4);
    cvt_bf16_k<<<1024, 256, 0, stream>>>(Wo, Wob, 1024 * 1024 / 4);

    // 2. QKV projections; Q pre-scaled by (1/sqrt(hd)) * log2(e) for exp2-domain softmax
    const float qscale = 0.125f * 1.4426950408889634f;
    gemm_bt_k<0><<<dim3(32, 8, 3), 256, 0, stream>>>(xb, Wqb, Wkb, Wvb, bq, bk, bv,
                                                     qscale, 1.f, 1.f, Qb, Kb, Vb);

    // 3. V -> V^T
    transpose_k<<<dim3(64, 16), 256, 0, stream>>>(Vb, Vtb);

    // 4. attention -> ctx
    attn2_k<<<dim3(32, 16), 256, 0, stream>>>(Qb, Kb, Vtb, Cb);

    // 5. output projection (f32 out)
    gemm_bt_k<1><<<dim3(32, 8, 1), 256, 0, stream>>>(Cb, Wob, Wob, Wob, bo, bo, bo,
                                                     1.f, 1.f, 1.f, out, out, out);
}

// Round 3
// 200.349 us; speedup vs baseline: 1.6444x; 1.0384x over previous
//
#include <hip/hip_runtime.h>
#include <hip/hip_bf16.h>

typedef __attribute__((ext_vector_type(8))) short short8;
typedef __attribute__((ext_vector_type(4))) float f32x4;
typedef __attribute__((ext_vector_type(16))) float f32x16;

#define MFMA16(a, b, c) __builtin_amdgcn_mfma_f32_16x16x32_bf16(a, b, c, 0, 0, 0)
#define MFMA32(a, b, c) __builtin_amdgcn_mfma_f32_32x32x16_bf16(a, b, c, 0, 0, 0)

typedef __attribute__((address_space(1))) const unsigned int GU32;
typedef __attribute__((address_space(3))) unsigned int LU32;
#define GLOAD16(g, l) __builtin_amdgcn_global_load_lds((GU32*)(g), (LU32*)(l), 16, 0, 0)

__device__ __forceinline__ unsigned short f2bf(float f) {
    union { float f; unsigned u; } a; a.f = f;
    unsigned r = a.u + 0x7fffu + ((a.u >> 16) & 1u);   // RNE
    return (unsigned short)(r >> 16);
}

__device__ __forceinline__ unsigned pk2(float a, float b) {
    __hip_bfloat162 h = __float22bfloat162_rn(make_float2(a, b));   // v_cvt_pk_bf16_f32
    union { __hip_bfloat162 h; unsigned u; } cv; cv.h = h; return cv.u;
}

// ---------------------------------------------------------------- convert f32 -> bf16
__global__ void cvt_bf16_k(const float* __restrict__ s, unsigned short* __restrict__ d, int n4) {
    int i = blockIdx.x * 256 + threadIdx.x;
    if (i >= n4) return;
    float4 v = reinterpret_cast<const float4*>(s)[i];
    ushort4 o;
    o.x = f2bf(v.x); o.y = f2bf(v.y); o.z = f2bf(v.z); o.w = f2bf(v.w);
    reinterpret_cast<ushort4*>(d)[i] = o;
}

// ---------------------------------------------------------------- GEMM: out[n][m] = (A[n][:] . B[m][:] + bias[m]) * scale
// 128x128 tile, BK=32, 2-phase double-buffered staging, 4 waves (2x2), 4x4 16x16x32 frags/wave
template<int F32OUT>
__global__ __launch_bounds__(256) void gemm_bt_k(
    const unsigned short* __restrict__ A,
    const unsigned short* __restrict__ B0, const unsigned short* __restrict__ B1,
    const unsigned short* __restrict__ B2,
    const float* __restrict__ bias0, const float* __restrict__ bias1, const float* __restrict__ bias2,
    float s0, float s1, float s2,
    void* o0, void* o1, void* o2)
{
    const int z = blockIdx.z;
    const unsigned short* B = z == 0 ? B0 : (z == 1 ? B1 : B2);
    const float* bias       = z == 0 ? bias0 : (z == 1 ? bias1 : bias2);
    const float scl         = z == 0 ? s0 : (z == 1 ? s1 : s2);
    void* outp              = z == 0 ? o0 : (z == 1 ? o1 : o2);

    __shared__ unsigned short As[2][4096];
    __shared__ unsigned short Bs[2][4096];

    const int tid = threadIdx.x;
    const int wid = tid >> 6, lane = tid & 63;
    const int lr = lane & 15, g = lane >> 4;
    const int wr = wid >> 1, wc = wid & 1;
    const int row0 = blockIdx.x * 128;
    const int col0 = blockIdx.y * 128;

    const int srow = tid >> 2;
    const int scol = (tid & 3) * 8;
    const unsigned short* aS0 = A + (row0 + srow) * 1024 + scol;
    const unsigned short* aS1 = aS0 + 64 * 1024;
    const unsigned short* bS0 = B + (col0 + srow) * 1024 + scol;
    const unsigned short* bS1 = bS0 + 64 * 1024;
    unsigned short* lA = &As[0][wid * 512];
    unsigned short* lB = &Bs[0][wid * 512];

#define GSTG(BUF, K0) do {                              \
        GLOAD16(aS0 + (K0), lA + (BUF) * 4096);         \
        GLOAD16(aS1 + (K0), lA + (BUF) * 4096 + 2048);  \
        GLOAD16(bS0 + (K0), lB + (BUF) * 4096);         \
        GLOAD16(bS1 + (K0), lB + (BUF) * 4096 + 2048);  \
    } while (0)

    f32x4 acc[4][4] = {};

    auto cmp = [&](const unsigned short* Ab, const unsigned short* Bb) {
        short8 af[4], bfr[4];
#pragma unroll
        for (int m = 0; m < 4; ++m)
            af[m] = *(const short8*)(Ab + (wr * 64 + m * 16 + lr) * 32 + g * 8);
#pragma unroll
        for (int n = 0; n < 4; ++n)
            bfr[n] = *(const short8*)(Bb + (wc * 64 + n * 16 + lr) * 32 + g * 8);
#pragma unroll
        for (int m = 0; m < 4; ++m)
#pragma unroll
            for (int n = 0; n < 4; ++n)
                acc[m][n] = MFMA16(af[m], bfr[n], acc[m][n]);
    };

    GSTG(0, 0);
    __syncthreads();
    for (int k0 = 0; k0 < 1024; k0 += 64) {
        if (k0 + 32 < 1024) GSTG(1, k0 + 32);
        cmp(As[0], Bs[0]);
        __syncthreads();
        if (k0 + 64 < 1024) GSTG(0, k0 + 64);
        cmp(As[1], Bs[1]);
        __syncthreads();
    }
#undef GSTG

#pragma unroll
    for (int n = 0; n < 4; ++n) {
        const int col = col0 + wc * 64 + n * 16 + lr;
        const float bv = bias[col];
#pragma unroll
        for (int m = 0; m < 4; ++m)
#pragma unroll
            for (int r = 0; r < 4; ++r) {
                const int row = row0 + wr * 64 + m * 16 + g * 4 + r;
                const float v = (acc[m][n][r] + bv) * scl;
                if (F32OUT) ((float*)outp)[row * 1024 + col] = v;
                else        ((unsigned short*)outp)[row * 1024 + col] = f2bf(v);
            }
    }
}

// ---------------------------------------------------------------- transpose bf16 [4096][1024] -> [1024][4096]
// Output token(key) index permuted by swapping bits 2<->3 within each 16-token block,
// so PV's B-operand k-slot order matches the S^T MFMA C-layout key order (no shuffles in attn).
__global__ __launch_bounds__(256) void transpose_k(const unsigned short* __restrict__ in,
                                                   unsigned short* __restrict__ out) {
    __shared__ unsigned short t[64][72];
    const int tid = threadIdx.x;
    const int r0 = blockIdx.x * 64;
    const int c0 = blockIdx.y * 64;
    {
        const int r = tid >> 2, cc = (tid & 3) * 16;
        const unsigned short* p = in + (r0 + r) * 1024 + c0 + cc;
        *(short8*)&t[r][cc]     = *(const short8*)p;
        *(short8*)&t[r][cc + 8] = *(const short8*)(p + 8);
    }
    __syncthreads();
    {
        const int c = tid >> 2, rr = (tid & 3) * 16;
        const int I0[8] = {0, 1, 2, 3, 8, 9, 10, 11};
        const int I1[8] = {4, 5, 6, 7, 12, 13, 14, 15};
        short8 v0, v1;
#pragma unroll
        for (int j = 0; j < 8; ++j) {
            v0[j] = (short)t[rr + I0[j]][c];
            v1[j] = (short)t[rr + I1[j]][c];
        }
        unsigned short* q = out + (c0 + c) * 4096 + r0 + rr;
        *(short8*)q       = v0;
        *(short8*)(q + 8) = v1;
    }
}

// ---------------------------------------------------------------- flash attention, swapped-operand 32x32 form
// grid (32 q-tiles of 128, 16 heads), 256 thr = 4 waves, QBLK=32 q-rows/wave, KVBLK=64.
// Q pre-scaled by 0.125*log2e; softmax in exp2 domain, fully in-register, state lane-local (q=lane&31).
// S^T = mfma(K,Q). ctx^T = mfma(Vt_perm, P): V key-permutation makes P fragments lane-local consecutive regs.
__global__ __launch_bounds__(256) void attn2_k(
    const unsigned short* __restrict__ Q, const unsigned short* __restrict__ K,
    const unsigned short* __restrict__ Vt, unsigned short* __restrict__ C)
{
    __shared__ unsigned short Ks[2][4096];   // [key 0..63][d 0..63], XOR-swizzled rows
    __shared__ unsigned short Vs[2][4096];   // [d 0..63][key 0..63 permuted], XOR-swizzled rows

    const int h = blockIdx.y;
    const int q0 = blockIdx.x * 128;
    const int tid = threadIdx.x, w = tid >> 6, lane = tid & 63;
    const int l31 = lane & 31, hi = lane >> 5;
    const int swz = (l31 & 7) << 4;

    // ---- staging (pre-swizzled global source, linear LDS dest)
    const int sr = tid >> 3;
    const int sb = (tid & 7) * 16;
    const int sc = (sb ^ ((sr & 7) << 4)) >> 1;
    const unsigned short* gK0 = K  + sr * 1024 + h * 64 + sc;
    const unsigned short* gK1 = K  + (sr + 32) * 1024 + h * 64 + sc;
    const unsigned short* gV0 = Vt + (h * 64 + sr) * 4096 + sc;
    const unsigned short* gV1 = Vt + (h * 64 + sr + 32) * 4096 + sc;
    unsigned short* kd = &Ks[0][w * 512];
    unsigned short* vd = &Vs[0][w * 512];

#define ASTAGE(BUF, KV) do {                                  \
        GLOAD16(gK0 + (KV) * 1024, kd + (BUF) * 4096);        \
        GLOAD16(gK1 + (KV) * 1024, kd + (BUF) * 4096 + 2048); \
        GLOAD16(gV0 + (KV),        vd + (BUF) * 4096);        \
        GLOAD16(gV1 + (KV),        vd + (BUF) * 4096 + 2048); \
    } while (0)

    // ---- Q fragments (B-operand): row q = q0+w*32+l31, k(d) = c*16 + hi*8 + j
    short8 qf[4];
    {
        const unsigned short* qp = Q + (q0 + w * 32 + l31) * 1024 + h * 64 + hi * 8;
#pragma unroll
        for (int c = 0; c < 4; ++c) qf[c] = *(const short8*)(qp + c * 16);
    }

    int koff[4];
#pragma unroll
    for (int c = 0; c < 4; ++c) koff[c] = ((c * 32 + hi * 16) ^ swz) >> 1;

    f32x16 acc0 = {}, acc1 = {};
    float m = -1e30f, l = 0.f;

    auto tile = [&](const unsigned short* Kc, const unsigned short* Vc) {
        // QK^T (swapped): S^T[key][q]
        f32x16 st0 = {}, st1 = {};
#pragma unroll
        for (int c = 0; c < 4; ++c) {
            st0 = MFMA32(*(const short8*)(Kc + l31 * 64 + koff[c]),        qf[c], st0);
            st1 = MFMA32(*(const short8*)(Kc + 2048 + l31 * 64 + koff[c]), qf[c], st1);
        }
        // tree max over this lane's 32 values, then one cross-half exchange
        float mm[8];
#pragma unroll
        for (int j = 0; j < 8; ++j)
            mm[j] = fmaxf(fmaxf(st0[j], st0[j + 8]), fmaxf(st1[j], st1[j + 8]));
        float mx = fmaxf(fmaxf(fmaxf(mm[0], mm[1]), fmaxf(mm[2], mm[3])),
                         fmaxf(fmaxf(mm[4], mm[5]), fmaxf(mm[6], mm[7])));
        mx = fmaxf(mx, __shfl_xor(mx, 32));
        if (__any(mx > m + 8.f)) {                         // defer-max THR=8
            const float mn = fmaxf(m, mx);
            const float al = __builtin_amdgcn_exp2f(m - mn);
            m = mn; l *= al;
#pragma unroll
            for (int i = 0; i < 16; ++i) { acc0[i] *= al; acc1[i] *= al; }
        }
        float p[32];
#pragma unroll
        for (int i = 0; i < 16; ++i) {
            p[i]      = __builtin_amdgcn_exp2f(st0[i] - m);
            p[16 + i] = __builtin_amdgcn_exp2f(st1[i] - m);
        }
        float ps[4] = {0.f, 0.f, 0.f, 0.f};
#pragma unroll
        for (int i = 0; i < 8; ++i)
#pragma unroll
            for (int j = 0; j < 4; ++j) ps[j] += p[i * 4 + j];
        float ts = (ps[0] + ps[1]) + (ps[2] + ps[3]);
        ts += __shfl_xor(ts, 32);
        l += ts;
        // PV: ctx^T += Vt_perm . P ; P frags are consecutive local regs (V key-permuted storage)
#pragma unroll
        for (int c = 0; c < 4; ++c) {
            union { unsigned u[4]; short8 s; } pf;
#pragma unroll
            for (int u = 0; u < 4; ++u) pf.u[u] = pk2(p[c * 8 + u * 2], p[c * 8 + u * 2 + 1]);
            acc0 = MFMA32(*(const short8*)(Vc + l31 * 64 + koff[c]),        pf.s, acc0);
            acc1 = MFMA32(*(const short8*)(Vc + 2048 + l31 * 64 + koff[c]), pf.s, acc1);
        }
    };

    ASTAGE(0, 0);
    __syncthreads();
    for (int kv = 0; kv < 4096; kv += 128) {
        if (kv + 64 < 4096) ASTAGE(1, kv + 64);
        tile(Ks[0], Vs[0]);
        __syncthreads();
        if (kv + 128 < 4096) ASTAGE(0, kv + 128);
        tile(Ks[1], Vs[1]);
        __syncthreads();
    }
#undef ASTAGE

    // epilogue: lane holds ctx^T[d][q=l31], d = dt*32 + rq*8 + 4*hi + e
    const float linv = 1.f / l;
    unsigned short* Cp = C + (q0 + w * 32 + l31) * 1024 + h * 64;
#pragma unroll
    for (int dt = 0; dt < 2; ++dt)
#pragma unroll
        for (int rq = 0; rq < 4; ++rq) {
            const f32x16& a = dt ? acc1 : acc0;
            uint2 o;
            o.x = pk2(a[rq * 4 + 0] * linv, a[rq * 4 + 1] * linv);
            o.y = pk2(a[rq * 4 + 2] * linv, a[rq * 4 + 3] * linv);
            *(uint2*)(Cp + dt * 32 + rq * 8 + hi * 4) = o;
        }
}

// ---------------------------------------------------------------- launch
extern "C" void kernel_launch(void* const* d_in, const int* in_sizes, int n_in,
                              void* d_out, int out_size, void* d_ws, size_t ws_size,
                              hipStream_t stream) {
    const float* x  = (const float*)d_in[0];
    const float* Wq = (const float*)d_in[1];
    const float* bq = (const float*)d_in[2];
    const float* Wk = (const float*)d_in[3];
    const float* bk = (const float*)d_in[4];
    const float* Wv = (const float*)d_in[5];
    const float* bv = (const float*)d_in[6];
    const float* Wo = (const float*)d_in[7];
    const float* bo = (const float*)d_in[8];
    float* out = (float*)d_out;

    const size_t MB = 1ull << 20;
    char* ws = (char*)d_ws;
    unsigned short* xb  = (unsigned short*)(ws);            // 8MB; reused as Vt after QKV GEMM
    unsigned short* Wqb = (unsigned short*)(ws + 8 * MB);
    unsigned short* Wkb = (unsigned short*)(ws + 10 * MB);
    unsigned short* Wvb = (unsigned short*)(ws + 12 * MB);
    unsigned short* Wob = (unsigned short*)(ws + 14 * MB);
    unsigned short* Qb  = (unsigned short*)(ws + 16 * MB);
    unsigned short* Kb  = (unsigned short*)(ws + 24 * MB);
    unsigned short* Vb  = (unsigned short*)(ws + 32 * MB);  // reused as ctx after transpose
    unsigned short* Vtb = xb;
    unsigned short* Cb  = Vb;

    // 1. convert to bf16
    cvt_bf16_k<<<4096, 256, 0, stream>>>(x,  xb,  4096 * 1024 / 4);
    cvt_bf16_k<<<1024, 256, 0, stream>>>(Wq, Wqb, 1024 * 1024 / 4);
    cvt_bf16_k<<<1024, 256, 0, stream>>>(Wk, Wkb, 1024 * 1024 / 4);
    cvt_bf16_k<<<1024, 256, 0, stream>>>(Wv, Wvb, 1024 * 1024 / 4);
    cvt_bf16_k<<<1024, 256, 0, stream>>>(Wo, Wob, 1024 * 1024 / 4);

    // 2. QKV projections; Q pre-scaled by (1/sqrt(hd)) * log2(e) for exp2-domain softmax
    const float qscale = 0.125f * 1.4426950408889634f;
    gemm_bt_k<0><<<dim3(32, 8, 3), 256, 0, stream>>>(xb, Wqb, Wkb, Wvb, bq, bk, bv,
                                                     qscale, 1.f, 1.f, Qb, Kb, Vb);

    // 3. V -> V^T (key index bits 2<->3 swapped)
    transpose_k<<<dim3(64, 16), 256, 0, stream>>>(Vb, Vtb);

    // 4. attention -> ctx
    attn2_k<<<dim3(32, 16), 256, 0, stream>>>(Qb, Kb, Vtb, Cb);

    // 5. output projection (f32 out)
    gemm_bt_k<1><<<dim3(32, 8, 1), 256, 0, stream>>>(Cb, Wob, Wob, Wob, bo, bo, bo,
                                                     1.f, 1.f, 1.f, out, out, out);
}

// Round 4
// 191.277 us; speedup vs baseline: 1.7224x; 1.0474x over previous
//
#include <hip/hip_runtime.h>
#include <hip/hip_bf16.h>

typedef __attribute__((ext_vector_type(8))) short short8;
typedef __attribute__((ext_vector_type(4))) float f32x4;
typedef __attribute__((ext_vector_type(16))) float f32x16;

#define MFMA16(a, b, c) __builtin_amdgcn_mfma_f32_16x16x32_bf16(a, b, c, 0, 0, 0)
#define MFMA32(a, b, c) __builtin_amdgcn_mfma_f32_32x32x16_bf16(a, b, c, 0, 0, 0)

typedef __attribute__((address_space(1))) const unsigned int GU32;
typedef __attribute__((address_space(3))) unsigned int LU32;
#define GLOAD16(g, l) __builtin_amdgcn_global_load_lds((GU32*)(g), (LU32*)(l), 16, 0, 0)

__device__ __forceinline__ unsigned short f2bf(float f) {
    union { float f; unsigned u; } a; a.f = f;
    unsigned r = a.u + 0x7fffu + ((a.u >> 16) & 1u);   // RNE
    return (unsigned short)(r >> 16);
}

__device__ __forceinline__ unsigned pk2(float a, float b) {
    __hip_bfloat162 h = __float22bfloat162_rn(make_float2(a, b));   // v_cvt_pk_bf16_f32
    union { __hip_bfloat162 h; unsigned u; } cv; cv.h = h; return cv.u;
}

// ---------------------------------------------------------------- convert f32 -> bf16
__global__ void cvt_bf16_k(const float* __restrict__ s, unsigned short* __restrict__ d, int n4) {
    int i = blockIdx.x * 256 + threadIdx.x;
    if (i >= n4) return;
    float4 v = reinterpret_cast<const float4*>(s)[i];
    ushort4 o;
    o.x = f2bf(v.x); o.y = f2bf(v.y); o.z = f2bf(v.z); o.w = f2bf(v.w);
    reinterpret_cast<ushort4*>(d)[i] = o;
}

// ---------------------------------------------------------------- GEMM: out[n][m] = (A[n][:] . B[m][:] + bias[m]) * scale
// 128x128 tile, BK=32, 2-phase double-buffered staging, 4 waves (2x2), 4x4 16x16x32 frags/wave.
// MODE 0: QKV fused — z<2 write bf16 row-major; z==2 writes V transposed [d][n'] with
//         n' = n bits2<->3 swapped (so attn PV B-fragments are lane-local consecutive regs).
// MODE 1: f32 row-major single output.
template<int MODE>
__global__ __launch_bounds__(256) void gemm_bt_k(
    const unsigned short* __restrict__ A,
    const unsigned short* __restrict__ B0, const unsigned short* __restrict__ B1,
    const unsigned short* __restrict__ B2,
    const float* __restrict__ bias0, const float* __restrict__ bias1, const float* __restrict__ bias2,
    float s0, float s1, float s2,
    void* o0, void* o1, void* o2)
{
    const int z = blockIdx.z;
    const unsigned short* B = z == 0 ? B0 : (z == 1 ? B1 : B2);
    const float* bias       = z == 0 ? bias0 : (z == 1 ? bias1 : bias2);
    const float scl         = z == 0 ? s0 : (z == 1 ? s1 : s2);
    void* outp              = z == 0 ? o0 : (z == 1 ? o1 : o2);

    __shared__ unsigned short As[2][4096];
    __shared__ unsigned short Bs[2][4096];

    const int tid = threadIdx.x;
    const int wid = tid >> 6, lane = tid & 63;
    const int lr = lane & 15, g = lane >> 4;
    const int wr = wid >> 1, wc = wid & 1;
    const int row0 = blockIdx.x * 128;
    const int col0 = blockIdx.y * 128;

    const int srow = tid >> 2;
    const int scol = (tid & 3) * 8;
    const unsigned short* aS0 = A + (row0 + srow) * 1024 + scol;
    const unsigned short* aS1 = aS0 + 64 * 1024;
    const unsigned short* bS0 = B + (col0 + srow) * 1024 + scol;
    const unsigned short* bS1 = bS0 + 64 * 1024;
    unsigned short* lA = &As[0][wid * 512];
    unsigned short* lB = &Bs[0][wid * 512];

#define GSTG(BUF, K0) do {                              \
        GLOAD16(aS0 + (K0), lA + (BUF) * 4096);         \
        GLOAD16(aS1 + (K0), lA + (BUF) * 4096 + 2048);  \
        GLOAD16(bS0 + (K0), lB + (BUF) * 4096);         \
        GLOAD16(bS1 + (K0), lB + (BUF) * 4096 + 2048);  \
    } while (0)

    f32x4 acc[4][4] = {};

    auto cmp = [&](const unsigned short* Ab, const unsigned short* Bb) {
        short8 af[4], bfr[4];
#pragma unroll
        for (int m = 0; m < 4; ++m)
            af[m] = *(const short8*)(Ab + (wr * 64 + m * 16 + lr) * 32 + g * 8);
#pragma unroll
        for (int n = 0; n < 4; ++n)
            bfr[n] = *(const short8*)(Bb + (wc * 64 + n * 16 + lr) * 32 + g * 8);
#pragma unroll
        for (int m = 0; m < 4; ++m)
#pragma unroll
            for (int n = 0; n < 4; ++n)
                acc[m][n] = MFMA16(af[m], bfr[n], acc[m][n]);
    };

    GSTG(0, 0);
    __syncthreads();
    for (int k0 = 0; k0 < 1024; k0 += 64) {
        if (k0 + 32 < 1024) GSTG(1, k0 + 32);
        cmp(As[0], Bs[0]);
        __syncthreads();
        if (k0 + 64 < 1024) GSTG(0, k0 + 64);
        cmp(As[1], Bs[1]);
        __syncthreads();
    }
#undef GSTG

    const bool vtrans = (MODE == 0) && (z == 2);
#pragma unroll
    for (int n = 0; n < 4; ++n) {
        const int col = col0 + wc * 64 + n * 16 + lr;
        const float bv = bias[col];
#pragma unroll
        for (int m = 0; m < 4; ++m) {
            if (vtrans) {
                // V: write Vt[col][n'] , n' = base16 + gp*4 + r, gp = swap of g bits
                const int base16 = row0 + wr * 64 + m * 16;
                const int gp = ((g & 1) << 1) | (g >> 1);
                float v0 = acc[m][n][0] + bv, v1 = acc[m][n][1] + bv;
                float v2 = acc[m][n][2] + bv, v3 = acc[m][n][3] + bv;
                uint2 o; o.x = pk2(v0, v1); o.y = pk2(v2, v3);
                *(uint2*)((unsigned short*)outp + col * 4096 + base16 + gp * 4) = o;
            } else {
#pragma unroll
                for (int r = 0; r < 4; ++r) {
                    const int row = row0 + wr * 64 + m * 16 + g * 4 + r;
                    const float v = (acc[m][n][r] + bv) * scl;
                    if (MODE == 1) ((float*)outp)[row * 1024 + col] = v;
                    else           ((unsigned short*)outp)[row * 1024 + col] = f2bf(v);
                }
            }
        }
    }
}

// ---------------------------------------------------------------- flash attention, swapped-operand 32x32 form
// grid (32 q-tiles of 128, 16 heads), 256 thr = 4 waves, QBLK=32 q-rows/wave, KVBLK=64.
// Q pre-scaled by 0.125*log2e; softmax in exp2 domain, fully in-register, state lane-local (q=lane&31).
// S^T = mfma(K,Q). ctx^T = mfma(Vt_perm, P). l accumulated by MFMA against all-ones A (lacc[0]).
__global__ __launch_bounds__(256) void attn2_k(
    const unsigned short* __restrict__ Q, const unsigned short* __restrict__ K,
    const unsigned short* __restrict__ Vt, unsigned short* __restrict__ C)
{
    __shared__ unsigned short Ks[2][4096];   // [key 0..63][d 0..63], XOR-swizzled rows
    __shared__ unsigned short Vs[2][4096];   // [d 0..63][key 0..63 permuted], XOR-swizzled rows

    const int h = blockIdx.y;
    const int q0 = blockIdx.x * 128;
    const int tid = threadIdx.x, w = tid >> 6, lane = tid & 63;
    const int l31 = lane & 31, hi = lane >> 5;
    const int swz = (l31 & 7) << 4;

    // ---- staging (pre-swizzled global source, linear LDS dest)
    const int sr = tid >> 3;
    const int sb = (tid & 7) * 16;
    const int sc = (sb ^ ((sr & 7) << 4)) >> 1;
    const unsigned short* gK0 = K  + sr * 1024 + h * 64 + sc;
    const unsigned short* gK1 = K  + (sr + 32) * 1024 + h * 64 + sc;
    const unsigned short* gV0 = Vt + (h * 64 + sr) * 4096 + sc;
    const unsigned short* gV1 = Vt + (h * 64 + sr + 32) * 4096 + sc;
    unsigned short* kd = &Ks[0][w * 512];
    unsigned short* vd = &Vs[0][w * 512];

#define ASTAGE(BUF, KV) do {                                  \
        GLOAD16(gK0 + (KV) * 1024, kd + (BUF) * 4096);        \
        GLOAD16(gK1 + (KV) * 1024, kd + (BUF) * 4096 + 2048); \
        GLOAD16(gV0 + (KV),        vd + (BUF) * 4096);        \
        GLOAD16(gV1 + (KV),        vd + (BUF) * 4096 + 2048); \
    } while (0)

    // ---- Q fragments (B-operand): row q = q0+w*32+l31, k(d) = c*16 + hi*8 + j
    short8 qf[4];
    {
        const unsigned short* qp = Q + (q0 + w * 32 + l31) * 1024 + h * 64 + hi * 8;
#pragma unroll
        for (int c = 0; c < 4; ++c) qf[c] = *(const short8*)(qp + c * 16);
    }

    int koff[4];
#pragma unroll
    for (int c = 0; c < 4; ++c) koff[c] = ((c * 32 + hi * 16) ^ swz) >> 1;

    const short8 ones = (short8)(short)0x3F80;   // bf16 1.0 splat

    f32x16 acc0 = {}, acc1 = {}, lacc = {};
    float m = -1e30f;

    auto tile = [&](const unsigned short* Kc, const unsigned short* Vc) {
        // QK^T (swapped): S^T[key][q]
        f32x16 st0 = {}, st1 = {};
        __builtin_amdgcn_s_setprio(1);
#pragma unroll
        for (int c = 0; c < 4; ++c) {
            st0 = MFMA32(*(const short8*)(Kc + l31 * 64 + koff[c]),        qf[c], st0);
            st1 = MFMA32(*(const short8*)(Kc + 2048 + l31 * 64 + koff[c]), qf[c], st1);
        }
        __builtin_amdgcn_s_setprio(0);
        // tree max over this lane's 32 values, then one cross-half exchange
        float mm[8];
#pragma unroll
        for (int j = 0; j < 8; ++j)
            mm[j] = fmaxf(fmaxf(st0[j], st0[j + 8]), fmaxf(st1[j], st1[j + 8]));
        float mx = fmaxf(fmaxf(fmaxf(mm[0], mm[1]), fmaxf(mm[2], mm[3])),
                         fmaxf(fmaxf(mm[4], mm[5]), fmaxf(mm[6], mm[7])));
        mx = fmaxf(mx, __shfl_xor(mx, 32));
        if (__any(mx > m + 8.f)) {                         // defer-max THR=8
            const float mn = fmaxf(m, mx);
            const float al = __builtin_amdgcn_exp2f(m - mn);
            m = mn;
            lacc[0] *= al;
#pragma unroll
            for (int i = 0; i < 16; ++i) { acc0[i] *= al; acc1[i] *= al; }
        }
        float p[32];
#pragma unroll
        for (int i = 0; i < 16; ++i) {
            p[i]      = __builtin_amdgcn_exp2f(st0[i] - m);
            p[16 + i] = __builtin_amdgcn_exp2f(st1[i] - m);
        }
        // PV: ctx^T += Vt_perm . P ; P frags are consecutive local regs (V key-permuted storage).
        // l accumulated via ones-A MFMA into lacc (row-broadcast; only lacc[0] is consumed).
        __builtin_amdgcn_s_setprio(1);
#pragma unroll
        for (int c = 0; c < 4; ++c) {
            union { unsigned u[4]; short8 s; } pf;
#pragma unroll
            for (int u = 0; u < 4; ++u) pf.u[u] = pk2(p[c * 8 + u * 2], p[c * 8 + u * 2 + 1]);
            acc0 = MFMA32(*(const short8*)(Vc + l31 * 64 + koff[c]),        pf.s, acc0);
            acc1 = MFMA32(*(const short8*)(Vc + 2048 + l31 * 64 + koff[c]), pf.s, acc1);
            lacc = MFMA32(ones, pf.s, lacc);
        }
        __builtin_amdgcn_s_setprio(0);
    };

    ASTAGE(0, 0);
    __syncthreads();
    for (int kv = 0; kv < 4096; kv += 128) {
        if (kv + 64 < 4096) ASTAGE(1, kv + 64);
        tile(Ks[0], Vs[0]);
        __syncthreads();
        if (kv + 128 < 4096) ASTAGE(0, kv + 128);
        tile(Ks[1], Vs[1]);
        __syncthreads();
    }
#undef ASTAGE

    // epilogue: lane holds ctx^T[d][q=l31], d = dt*32 + rq*8 + 4*hi + e ; l = lacc[0]
    const float linv = 1.f / lacc[0];
    unsigned short* Cp = C + (q0 + w * 32 + l31) * 1024 + h * 64;
#pragma unroll
    for (int dt = 0; dt < 2; ++dt)
#pragma unroll
        for (int rq = 0; rq < 4; ++rq) {
            const f32x16& a = dt ? acc1 : acc0;
            uint2 o;
            o.x = pk2(a[rq * 4 + 0] * linv, a[rq * 4 + 1] * linv);
            o.y = pk2(a[rq * 4 + 2] * linv, a[rq * 4 + 3] * linv);
            *(uint2*)(Cp + dt * 32 + rq * 8 + hi * 4) = o;
        }
}

// ---------------------------------------------------------------- launch
extern "C" void kernel_launch(void* const* d_in, const int* in_sizes, int n_in,
                              void* d_out, int out_size, void* d_ws, size_t ws_size,
                              hipStream_t stream) {
    const float* x  = (const float*)d_in[0];
    const float* Wq = (const float*)d_in[1];
    const float* bq = (const float*)d_in[2];
    const float* Wk = (const float*)d_in[3];
    const float* bk = (const float*)d_in[4];
    const float* Wv = (const float*)d_in[5];
    const float* bv = (const float*)d_in[6];
    const float* Wo = (const float*)d_in[7];
    const float* bo = (const float*)d_in[8];
    float* out = (float*)d_out;

    const size_t MB = 1ull << 20;
    char* ws = (char*)d_ws;
    unsigned short* xb  = (unsigned short*)(ws);            // 8MB; free after QKV -> reused as ctx
    unsigned short* Wqb = (unsigned short*)(ws + 8 * MB);
    unsigned short* Wkb = (unsigned short*)(ws + 10 * MB);
    unsigned short* Wvb = (unsigned short*)(ws + 12 * MB);
    unsigned short* Wob = (unsigned short*)(ws + 14 * MB);
    unsigned short* Qb  = (unsigned short*)(ws + 16 * MB);
    unsigned short* Kb  = (unsigned short*)(ws + 24 * MB);
    unsigned short* Vtb = (unsigned short*)(ws + 32 * MB);  // V^T (key-permuted), written by QKV GEMM
    unsigned short* Cb  = xb;

    // 1. convert to bf16
    cvt_bf16_k<<<4096, 256, 0, stream>>>(x,  xb,  4096 * 1024 / 4);
    cvt_bf16_k<<<1024, 256, 0, stream>>>(Wq, Wqb, 1024 * 1024 / 4);
    cvt_bf16_k<<<1024, 256, 0, stream>>>(Wk, Wkb, 1024 * 1024 / 4);
    cvt_bf16_k<<<1024, 256, 0, stream>>>(Wv, Wvb, 1024 * 1024 / 4);
    cvt_bf16_k<<<1024, 256, 0, stream>>>(Wo, Wob, 1024 * 1024 / 4);

    // 2. QKV projections; Q pre-scaled by (1/sqrt(hd))*log2(e); V written transposed+permuted
    const float qscale = 0.125f * 1.4426950408889634f;
    gemm_bt_k<0><<<dim3(32, 8, 3), 256, 0, stream>>>(xb, Wqb, Wkb, Wvb, bq, bk, bv,
                                                     qscale, 1.f, 1.f, Qb, Kb, Vtb);

    // 3. attention -> ctx
    attn2_k<<<dim3(32, 16), 256, 0, stream>>>(Qb, Kb, Vtb, Cb);

    // 4. output projection (f32 out)
    gemm_bt_k<1><<<dim3(32, 8, 1), 256, 0, stream>>>(Cb, Wob, Wob, Wob, bo, bo, bo,
                                                     1.f, 1.f, 1.f, out, out, out);
}